// Round 6
// baseline (276.101 us; speedup 1.0000x reference)
//
#include <hip/hip_runtime.h>
#include <cstdint>
#include <cstddef>

#define S_LEN   2048
#define D_MODEL 1024
#define N_HEADS 16
#define HEAD_DIM 64
#define BATCH   4
#define M_ROWS  (BATCH * S_LEN)   // 8192

typedef _Float16 half8  __attribute__((ext_vector_type(8)));
typedef _Float16 half4v __attribute__((ext_vector_type(4)));
typedef float    float4v __attribute__((ext_vector_type(4)));

#define AS1 __attribute__((address_space(1)))
#define AS3 __attribute__((address_space(3)))

#define QSCL 0.1803368801111832f   // (1/sqrt(64)) * log2(e), folded into Q proj

// byte-offset swizzle for 128-B LDS rows (8 x 16-B blocks per row) [attention]
__device__ __forceinline__ int swz(int row, int byteInRow) {
    return row * 128 + ((((byteInRow >> 4) ^ (row & 7)) << 4)) + (byteInRow & 15);
}

// V key-permutation within 64-blocks (PV A-operand alignment with S^T C-frag)
__device__ __forceinline__ int vperm(int a) {
    return (a & 0x20) | ((a & 0x0C) << 1) | ((a & 0x10) >> 2) | (a & 3);
}

// ---- GEMM LDS swizzle over 128-B macro-rows (2 x 64-B rows) ----
// element (r, c) [c in 0..31] -> byte addr:
//   macro = r>>1; b = (r&1)*4 + (c>>3); sb = b ^ (macro&7)
//   addr = macro*128 + sb*16 + (c&7)*2
// Fragment read (row, 16B block q=c>>3): 16 rows -> each bank-group hit by
// exactly 2 lanes -> conflict-free (m136: 2-way is free).
__device__ __forceinline__ const half8* gfrag(const _Float16* base, int row, int q) {
    int macro = row >> 1;
    int sb = (((row & 1) << 2) | q) ^ (macro & 7);
    return (const half8*)((const char*)base + macro * 128 + sb * 16);
}
// inverse: staging dest byte d (lane-contiguous) -> source element offset in tile
__device__ __forceinline__ size_t gsrc(int d, int K) {
    int macro = d >> 7;
    int sb = (d >> 4) & 7;
    int b = sb ^ (macro & 7);
    int r = (macro << 1) | (b >> 2);
    int cblk = b & 3;
    return (size_t)r * K + cblk * 8;
}

// ---------------------------------------------------------------- fused convert
__global__ __launch_bounds__(256) void cvt_all(const float* __restrict__ x,
                                               const float* __restrict__ wq,
                                               const float* __restrict__ wk,
                                               const float* __restrict__ wv,
                                               const float* __restrict__ wo,
                                               _Float16* __restrict__ dst) {
    const int NX = M_ROWS * D_MODEL / 4;
    const int NW = D_MODEL * D_MODEL / 4;
    int i = blockIdx.x * 256 + threadIdx.x;
    int j = i;
    const float4v* src;
    if (j < NX) src = (const float4v*)x;
    else {
        j -= NX;
        if (j < NW) src = (const float4v*)wq;
        else { j -= NW;
            if (j < NW) src = (const float4v*)wk;
            else { j -= NW;
                if (j < NW) src = (const float4v*)wv;
                else { j -= NW; src = (const float4v*)wo; }
            }
        }
    }
    float4v v = src[j];
    half4v h;
    h[0] = (_Float16)v[0]; h[1] = (_Float16)v[1];
    h[2] = (_Float16)v[2]; h[3] = (_Float16)v[3];
    ((half4v*)dst)[i] = h;
}

// ---------------------------------------------------------------- GEMM  C = A * B^T
// MODE 0: f16 out -> Q (pre-scaled by QSCL) / K in [b,h,s,hd]
// MODE 1: f16 out -> Vt [b,h,hd,s'] with vperm key order within 64-blocks
// MODE 2: f32 out row-major + bias
template <int MODE>
__global__ __launch_bounds__(256) void gemm_bt(const _Float16* __restrict__ A,
                                               const _Float16* __restrict__ Bw,
                                               _Float16* __restrict__ O1,
                                               _Float16* __restrict__ O2,
                                               float* __restrict__ Of,
                                               const float* __restrict__ bias,
                                               int M, int N, int K) {
    __shared__ __align__(16) _Float16 As[128 * 32];
    __shared__ __align__(16) _Float16 Bs[128 * 32];

    const int tid  = threadIdx.x;
    const int wave = tid >> 6;
    const int lane = tid & 63;
    const int quad = lane >> 4;
    const int l16  = lane & 15;

    const int rowBase = blockIdx.x * 128;
    const int colBase = blockIdx.y * 128;
    const int rowOff  = (wave >> 1) * 64;
    const int colOff  = (wave & 1) * 64;

    float4v acc[4][4] = {};

    // staging: dest byte d = it*4096 + tid*16 (lane-contiguous); source offset
    // carries the macro-row swizzle so fragments land conflict-free.
    const size_t off0 = gsrc(tid * 16, K);
    const size_t off1 = gsrc(4096 + tid * 16, K);

    const _Float16* aSrc0 = A + (size_t)rowBase * K + off0;
    const _Float16* aSrc1 = A + (size_t)rowBase * K + off1;
    const _Float16* bSrc0 = Bw + (size_t)colBase * K + off0;
    const _Float16* bSrc1 = Bw + (size_t)colBase * K + off1;

    _Float16* aDst0 = As + wave * 512;          // byte wave*1024 (+lane*16 by HW)
    _Float16* aDst1 = As + 2048 + wave * 512;
    _Float16* bDst0 = Bs + wave * 512;
    _Float16* bDst1 = Bs + 2048 + wave * 512;

    for (int k0 = 0; k0 < K; k0 += 32) {
        __builtin_amdgcn_global_load_lds((const AS1 void*)(aSrc0 + k0), (AS3 void*)aDst0, 16, 0, 0);
        __builtin_amdgcn_global_load_lds((const AS1 void*)(aSrc1 + k0), (AS3 void*)aDst1, 16, 0, 0);
        __builtin_amdgcn_global_load_lds((const AS1 void*)(bSrc0 + k0), (AS3 void*)bDst0, 16, 0, 0);
        __builtin_amdgcn_global_load_lds((const AS1 void*)(bSrc1 + k0), (AS3 void*)bDst1, 16, 0, 0);
        __syncthreads();

        half8 af[4], bf[4];
#pragma unroll
        for (int mi = 0; mi < 4; ++mi)
            af[mi] = *gfrag(As, rowOff + mi * 16 + l16, quad);
#pragma unroll
        for (int ni = 0; ni < 4; ++ni)
            bf[ni] = *gfrag(Bs, colOff + ni * 16 + l16, quad);

#pragma unroll
        for (int mi = 0; mi < 4; ++mi)
#pragma unroll
            for (int ni = 0; ni < 4; ++ni)
                acc[mi][ni] = __builtin_amdgcn_mfma_f32_16x16x32_f16(
                    af[mi], bf[ni], acc[mi][ni], 0, 0, 0);
        __syncthreads();
    }

#pragma unroll
    for (int mi = 0; mi < 4; ++mi)
#pragma unroll
        for (int ni = 0; ni < 4; ++ni) {
            const int col = colBase + colOff + ni * 16 + l16;
#pragma unroll
            for (int i = 0; i < 4; ++i) {
                const int row = rowBase + rowOff + mi * 16 + quad * 4 + i;
                float v = acc[mi][ni][i];
                if (MODE == 0) {
                    int b_ = row >> 11, s_ = row & 2047;
                    int proj = col >> 10, d = col & 1023;
                    int h_ = d >> 6, hd = d & 63;
                    _Float16* dst = proj ? O2 : O1;
                    if (proj == 0) v *= QSCL;
                    dst[(((size_t)(b_ * 16 + h_) * 2048 + s_) << 6) + hd] = (_Float16)v;
                } else if (MODE == 1) {
                    int h_ = row >> 6, hd = row & 63;
                    int b_ = col >> 11, s_ = col & 2047;
                    int sp = (s_ & ~63) | vperm(s_ & 63);
                    O1[(((size_t)(b_ * 16 + h_) * 64 + hd) << 11) + sp] = (_Float16)v;
                } else {
                    Of[(size_t)row * N + col] = v + bias[col];
                }
            }
        }
}

// ---------------------------------------------------------------- attention tile step
// One wave, one 16-row q-tile vs the 64-key KV tile in LDS.
// S^T = K·Q^T via mfma(kf, qf): C gives qrow = lane&15, key = nt*16+quad*4+reg.
// exps packed in-register -> PV A-operand (keys vperm-matched in Vt). No P LDS.
template <bool MASKED>
__device__ __forceinline__ void attn_step5(const half8 qf[2],
                                           const _Float16* __restrict__ Ks,
                                           const _Float16* __restrict__ Vs,
                                           int krow0, int qt, int quad, int c,
                                           float4v o[4], float& l) {
    float4v sT[4] = {};
#pragma unroll
    for (int nt = 0; nt < 4; ++nt)
#pragma unroll
        for (int ks = 0; ks < 2; ++ks) {
            half8 kf = *(const half8*)((const char*)Ks + swz(nt * 16 + c, ks * 64 + quad * 16));
            sT[nt] = __builtin_amdgcn_mfma_f32_16x16x32_f16(kf, qf[ks], sT[nt], 0, 0, 0);
        }

    const int qrow_g = qt + c;
#pragma unroll
    for (int kk = 0; kk < 2; ++kk) {
        float e[2][4];
#pragma unroll
        for (int jh = 0; jh < 2; ++jh) {
            const int nt = 2 * kk + jh;
#pragma unroll
            for (int i = 0; i < 4; ++i) {
                float ev = __builtin_amdgcn_exp2f(sT[nt][i]);
                if (MASKED)
                    ev = (krow0 + nt * 16 + quad * 4 + i <= qrow_g) ? ev : 0.0f;
                e[jh][i] = ev;
                l += ev;
            }
        }
        auto p0 = __builtin_amdgcn_cvt_pkrtz(e[0][0], e[0][1]);
        auto p1 = __builtin_amdgcn_cvt_pkrtz(e[0][2], e[0][3]);
        auto p2 = __builtin_amdgcn_cvt_pkrtz(e[1][0], e[1][1]);
        auto p3 = __builtin_amdgcn_cvt_pkrtz(e[1][2], e[1][3]);
        half8 pf;
        pf[0] = p0[0]; pf[1] = p0[1]; pf[2] = p1[0]; pf[3] = p1[1];
        pf[4] = p2[0]; pf[5] = p2[1]; pf[6] = p3[0]; pf[7] = p3[1];
#pragma unroll
        for (int dt = 0; dt < 4; ++dt) {
            half8 vf = *(const half8*)((const char*)Vs + swz(dt * 16 + c, kk * 64 + quad * 16));
            o[dt] = __builtin_amdgcn_mfma_f32_16x16x32_f16(pf, vf, o[dt], 0, 0, 0);
        }
    }
}

// ---------------------------------------------------------------- flash attention
// Mirror-paired causal q-tiles split in half: block (h, halfpair, b), wave owns
// one 16-row tile of each of qA/qB. Double-buffered KV, one barrier per iter.
__global__ __launch_bounds__(256, 4) void attn_flash5(const _Float16* __restrict__ Q,
                                                      const _Float16* __restrict__ Kg,
                                                      const _Float16* __restrict__ Vt,
                                                      _Float16* __restrict__ Ctx) {
    __shared__ __align__(16) _Float16 Ks[2 * 64 * 64];  // 16 KB dbuf
    __shared__ __align__(16) _Float16 Vs[2 * 64 * 64];  // 16 KB dbuf

    const int tid  = threadIdx.x;
    const int wave = tid >> 6;
    const int lane = tid & 63;
    const int quad = lane >> 4;
    const int c    = lane & 15;

    const int h    = blockIdx.x;
    const int hp   = blockIdx.y;
    const int bb   = blockIdx.z;
    const int pair = hp >> 1;
    const int hf   = hp & 1;

    const int qA = pair * 128 + hf * 64 + wave * 16;
    const int qB = (15 - pair) * 128 + hf * 64 + wave * 16;
    const int nkbB = (15 - pair) * 2 + hf + 1;

    const _Float16* Qb  = Q  + ((size_t)(bb * 16 + h) << 17);
    const _Float16* Kb  = Kg + ((size_t)(bb * 16 + h) << 17);
    const _Float16* Vtb = Vt + ((size_t)(bb * 16 + h) << 17);

    half8 qfA[2], qfB[2];
    {
        const _Float16* qa = Qb + (size_t)(qA + c) * 64;
        qfA[0] = *(const half8*)(qa + quad * 8);
        qfA[1] = *(const half8*)(qa + 32 + quad * 8);
        const _Float16* qb = Qb + (size_t)(qB + c) * 64;
        qfB[0] = *(const half8*)(qb + quad * 8);
        qfB[1] = *(const half8*)(qb + 32 + quad * 8);
    }

    size_t koff[2], voff[2];
#pragma unroll
    for (int it = 0; it < 2; ++it) {
        int F = it * 4096 + tid * 16;
        int r = F >> 7;
        int blk = (tid & 7) ^ (r & 7);
        koff[it] = (size_t)r * 64 + blk * 8;
        voff[it] = (size_t)r * 2048 + blk * 8;
    }

    float4v oA[4] = {}, oB[4] = {};
    float lA = 0.0f, lB = 0.0f;

    auto stage = [&](int kb, int buf) {
        const size_t kbase = (size_t)kb * 64 * 64;
#pragma unroll
        for (int it = 0; it < 2; ++it) {
            __builtin_amdgcn_global_load_lds(
                (const AS1 void*)(Kb + kbase + koff[it]),
                (AS3 void*)((char*)Ks + buf * 8192 + it * 4096 + wave * 1024), 16, 0, 0);
            __builtin_amdgcn_global_load_lds(
                (const AS1 void*)(Vtb + kb * 64 + voff[it]),
                (AS3 void*)((char*)Vs + buf * 8192 + it * 4096 + wave * 1024), 16, 0, 0);
        }
    };

    stage(0, 0);
    for (int kb = 0; kb < nkbB; ++kb) {
        __syncthreads();                       // buf kb ready; prev buf free
        if (kb + 1 < nkbB) stage(kb + 1, (kb + 1) & 1);

        const _Float16* Ksb = Ks + (kb & 1) * 4096;
        const _Float16* Vsb = Vs + (kb & 1) * 4096;
        const int krow0 = kb * 64;

        if (krow0 <= qB + 15) {
            if (krow0 + 63 <= qB)
                attn_step5<false>(qfB, Ksb, Vsb, krow0, qB, quad, c, oB, lB);
            else
                attn_step5<true >(qfB, Ksb, Vsb, krow0, qB, quad, c, oB, lB);
        }
        if (krow0 <= qA + 15) {
            if (krow0 + 63 <= qA)
                attn_step5<false>(qfA, Ksb, Vsb, krow0, qA, quad, c, oA, lA);
            else
                attn_step5<true >(qfA, Ksb, Vsb, krow0, qA, quad, c, oA, lA);
        }
    }

    // ---- l reduction across quads (lanes with same c hold same qrow)
    lA += __shfl_xor(lA, 16); lA += __shfl_xor(lA, 32);
    lB += __shfl_xor(lB, 16); lB += __shfl_xor(lB, 32);

    // ---- normalize + write ctx [b, s, h*64+hd]
#pragma unroll
    for (int t = 0; t < 2; ++t) {
        const float lv = t ? lB : lA;
        float4v* o = t ? oB : oA;
        const int qt = t ? qB : qA;
#pragma unroll
        for (int i = 0; i < 4; ++i) {
            const float inv = 1.0f / __shfl(lv, quad * 4 + i);
            const int row_g = qt + quad * 4 + i;
            _Float16* dst = Ctx + (size_t)(bb * 2048 + row_g) * 1024 + h * 64;
#pragma unroll
            for (int dt = 0; dt < 4; ++dt)
                dst[dt * 16 + c] = (_Float16)(o[dt][i] * inv);
        }
    }
}

// ---------------------------------------------------------------- launch
extern "C" void kernel_launch(void* const* d_in, const int* in_sizes, int n_in,
                              void* d_out, int out_size, void* d_ws, size_t ws_size,
                              hipStream_t stream) {
    const float* x  = (const float*)d_in[0];
    const float* Wq = (const float*)d_in[1];
    const float* Wk = (const float*)d_in[2];
    const float* Wv = (const float*)d_in[3];
    const float* Wo = (const float*)d_in[4];
    const float* bo = (const float*)d_in[5];
    float* out = (float*)d_out;

    _Float16* Xh   = (_Float16*)d_ws;
    _Float16* Wqkh = Xh + (size_t)M_ROWS * D_MODEL;      // Wq | Wk
    _Float16* Wvh  = Wqkh + (size_t)2 * D_MODEL * D_MODEL;
    _Float16* Woh  = Wvh + (size_t)D_MODEL * D_MODEL;
    _Float16* Qh   = Woh + (size_t)D_MODEL * D_MODEL;    // [b,h,s,hd], pre-scaled
    _Float16* Kh   = Qh + (size_t)M_ROWS * D_MODEL;      // [b,h,s,hd]
    _Float16* Vth  = Kh + (size_t)M_ROWS * D_MODEL;      // [b,h,hd,s'] vperm order
    _Float16* Ch   = Vth + (size_t)M_ROWS * D_MODEL;     // [b*s, d]

    const int TOT4 = (M_ROWS * D_MODEL + 4 * D_MODEL * D_MODEL) / 4;
    cvt_all<<<TOT4 / 256, 256, 0, stream>>>(x, Wq, Wk, Wv, Wo, Xh);

    gemm_bt<0><<<dim3(M_ROWS / 128, 2048 / 128), 256, 0, stream>>>(
        Xh, Wqkh, Qh, Kh, nullptr, nullptr, M_ROWS, 2048, D_MODEL);
    gemm_bt<1><<<dim3(D_MODEL / 128, M_ROWS / 128), 256, 0, stream>>>(
        Wvh, Xh, Vth, nullptr, nullptr, nullptr, D_MODEL, M_ROWS, D_MODEL);

    attn_flash5<<<dim3(N_HEADS, 16, BATCH), 256, 0, stream>>>(Qh, Kh, Vth, Ch);

    gemm_bt<2><<<dim3(M_ROWS / 128, D_MODEL / 128), 256, 0, stream>>>(
        Ch, Woh, nullptr, nullptr, out, bo, M_ROWS, D_MODEL, D_MODEL);
}

// Round 7
// 252.060 us; speedup vs baseline: 1.0954x; 1.0954x over previous
//
#include <hip/hip_runtime.h>
#include <cstdint>
#include <cstddef>

#define S_LEN   2048
#define D_MODEL 1024
#define N_HEADS 16
#define HEAD_DIM 64
#define BATCH   4
#define M_ROWS  (BATCH * S_LEN)   // 8192

typedef _Float16 half8  __attribute__((ext_vector_type(8)));
typedef _Float16 half4v __attribute__((ext_vector_type(4)));
typedef float    float4v __attribute__((ext_vector_type(4)));

#define AS1 __attribute__((address_space(1)))
#define AS3 __attribute__((address_space(3)))

#define QSCL 0.1803368801111832f   // (1/sqrt(64)) * log2(e), folded into Q proj

// byte-offset swizzle for 128-B LDS rows (8 x 16-B blocks per row) [attention]
__device__ __forceinline__ int swz(int row, int byteInRow) {
    return row * 128 + ((((byteInRow >> 4) ^ (row & 7)) << 4)) + (byteInRow & 15);
}

// V key-permutation within 64-blocks (PV A-operand alignment with S^T C-frag)
__device__ __forceinline__ int vperm(int a) {
    return (a & 0x20) | ((a & 0x0C) << 1) | ((a & 0x10) >> 2) | (a & 3);
}

// ---- GEMM LDS swizzle over 128-B macro-rows (2 x 64-B rows) ----
__device__ __forceinline__ const half8* gfrag(const _Float16* base, int row, int q) {
    int macro = row >> 1;
    int sb = (((row & 1) << 2) | q) ^ (macro & 7);
    return (const half8*)((const char*)base + macro * 128 + sb * 16);
}
// inverse: staging dest byte d (lane-contiguous) -> source element offset in tile
__device__ __forceinline__ size_t gsrc(int d, int K) {
    int macro = d >> 7;
    int sb = (d >> 4) & 7;
    int b = sb ^ (macro & 7);
    int r = (macro << 1) | (b >> 2);
    int cblk = b & 3;
    return (size_t)r * K + cblk * 8;
}

// ---------------------------------------------------------------- fused convert
__global__ __launch_bounds__(256) void cvt_all(const float* __restrict__ x,
                                               const float* __restrict__ wq,
                                               const float* __restrict__ wk,
                                               const float* __restrict__ wv,
                                               const float* __restrict__ wo,
                                               _Float16* __restrict__ dst) {
    const int NX = M_ROWS * D_MODEL / 4;
    const int NW = D_MODEL * D_MODEL / 4;
    int i = blockIdx.x * 256 + threadIdx.x;
    int j = i;
    const float4v* src;
    if (j < NX) src = (const float4v*)x;
    else {
        j -= NX;
        if (j < NW) src = (const float4v*)wq;
        else { j -= NW;
            if (j < NW) src = (const float4v*)wk;
            else { j -= NW;
                if (j < NW) src = (const float4v*)wv;
                else { j -= NW; src = (const float4v*)wo; }
            }
        }
    }
    float4v v = src[j];
    half4v h;
    h[0] = (_Float16)v[0]; h[1] = (_Float16)v[1];
    h[2] = (_Float16)v[2]; h[3] = (_Float16)v[3];
    ((half4v*)dst)[i] = h;
}

// ---------------------------------------------------------------- GEMM  C = A * B^T
// Double-buffered staging (attention-style): prefetch tile k+1 after the
// single barrier, compute tile k. One barrier per BK=32 iter.
// MODE 0: f16 out -> Q (pre-scaled by QSCL) / K in [b,h,s,hd]
// MODE 1: f16 out -> Vt [b,h,hd,s'] with vperm key order within 64-blocks
// MODE 2: f32 out row-major + bias
template <int MODE>
__global__ __launch_bounds__(256) void gemm_bt(const _Float16* __restrict__ A,
                                               const _Float16* __restrict__ Bw,
                                               _Float16* __restrict__ O1,
                                               _Float16* __restrict__ O2,
                                               float* __restrict__ Of,
                                               const float* __restrict__ bias,
                                               int M, int N, int K) {
    __shared__ __align__(16) _Float16 As[2][128 * 32];  // 16 KB dbuf
    __shared__ __align__(16) _Float16 Bs[2][128 * 32];  // 16 KB dbuf

    const int tid  = threadIdx.x;
    const int wave = tid >> 6;
    const int lane = tid & 63;
    const int quad = lane >> 4;
    const int l16  = lane & 15;

    const int rowBase = blockIdx.x * 128;
    const int colBase = blockIdx.y * 128;
    const int rowOff  = (wave >> 1) * 64;
    const int colOff  = (wave & 1) * 64;

    float4v acc[4][4] = {};

    // staging: dest byte d = it*4096 + tid*16 (lane-contiguous); source offset
    // carries the macro-row swizzle so fragments land conflict-free.
    const size_t off0 = gsrc(tid * 16, K);
    const size_t off1 = gsrc(4096 + tid * 16, K);

    const _Float16* aSrc0 = A + (size_t)rowBase * K + off0;
    const _Float16* aSrc1 = A + (size_t)rowBase * K + off1;
    const _Float16* bSrc0 = Bw + (size_t)colBase * K + off0;
    const _Float16* bSrc1 = Bw + (size_t)colBase * K + off1;

    auto stage = [&](int k0, int buf) {
        __builtin_amdgcn_global_load_lds((const AS1 void*)(aSrc0 + k0),
            (AS3 void*)(As[buf] + wave * 512), 16, 0, 0);
        __builtin_amdgcn_global_load_lds((const AS1 void*)(aSrc1 + k0),
            (AS3 void*)(As[buf] + 2048 + wave * 512), 16, 0, 0);
        __builtin_amdgcn_global_load_lds((const AS1 void*)(bSrc0 + k0),
            (AS3 void*)(Bs[buf] + wave * 512), 16, 0, 0);
        __builtin_amdgcn_global_load_lds((const AS1 void*)(bSrc1 + k0),
            (AS3 void*)(Bs[buf] + 2048 + wave * 512), 16, 0, 0);
    };

    const int niter = K >> 5;
    stage(0, 0);
    for (int it = 0; it < niter; ++it) {
        __syncthreads();                 // buf it&1 staged; prev buf free
        if (it + 1 < niter) stage((it + 1) << 5, (it + 1) & 1);

        const _Float16* Ab = As[it & 1];
        const _Float16* Bb = Bs[it & 1];

        half8 af[4], bf[4];
#pragma unroll
        for (int mi = 0; mi < 4; ++mi)
            af[mi] = *gfrag(Ab, rowOff + mi * 16 + l16, quad);
#pragma unroll
        for (int ni = 0; ni < 4; ++ni)
            bf[ni] = *gfrag(Bb, colOff + ni * 16 + l16, quad);

#pragma unroll
        for (int mi = 0; mi < 4; ++mi)
#pragma unroll
            for (int ni = 0; ni < 4; ++ni)
                acc[mi][ni] = __builtin_amdgcn_mfma_f32_16x16x32_f16(
                    af[mi], bf[ni], acc[mi][ni], 0, 0, 0);
    }

#pragma unroll
    for (int mi = 0; mi < 4; ++mi)
#pragma unroll
        for (int ni = 0; ni < 4; ++ni) {
            const int col = colBase + colOff + ni * 16 + l16;
#pragma unroll
            for (int i = 0; i < 4; ++i) {
                const int row = rowBase + rowOff + mi * 16 + quad * 4 + i;
                float v = acc[mi][ni][i];
                if (MODE == 0) {
                    int b_ = row >> 11, s_ = row & 2047;
                    int proj = col >> 10, d = col & 1023;
                    int h_ = d >> 6, hd = d & 63;
                    _Float16* dst = proj ? O2 : O1;
                    if (proj == 0) v *= QSCL;
                    dst[(((size_t)(b_ * 16 + h_) * 2048 + s_) << 6) + hd] = (_Float16)v;
                } else if (MODE == 1) {
                    int h_ = row >> 6, hd = row & 63;
                    int b_ = col >> 11, s_ = col & 2047;
                    int sp = (s_ & ~63) | vperm(s_ & 63);
                    O1[(((size_t)(b_ * 16 + h_) * 64 + hd) << 11) + sp] = (_Float16)v;
                } else {
                    Of[(size_t)row * N + col] = v + bias[col];
                }
            }
        }
}

// ---------------------------------------------------------------- attention tile step
// S^T = K·Q^T via mfma(kf, qf): C gives qrow = lane&15, key = nt*16+quad*4+reg.
// exps packed in-register -> PV A-operand (keys vperm-matched in Vt). No P LDS.
template <bool MASKED>
__device__ __forceinline__ void attn_step5(const half8 qf[2],
                                           const _Float16* __restrict__ Ks,
                                           const _Float16* __restrict__ Vs,
                                           int krow0, int qt, int quad, int c,
                                           float4v o[4], float& l) {
    float4v sT[4] = {};
#pragma unroll
    for (int nt = 0; nt < 4; ++nt)
#pragma unroll
        for (int ks = 0; ks < 2; ++ks) {
            half8 kf = *(const half8*)((const char*)Ks + swz(nt * 16 + c, ks * 64 + quad * 16));
            sT[nt] = __builtin_amdgcn_mfma_f32_16x16x32_f16(kf, qf[ks], sT[nt], 0, 0, 0);
        }

    const int qrow_g = qt + c;
#pragma unroll
    for (int kk = 0; kk < 2; ++kk) {
        float e[2][4];
#pragma unroll
        for (int jh = 0; jh < 2; ++jh) {
            const int nt = 2 * kk + jh;
#pragma unroll
            for (int i = 0; i < 4; ++i) {
                float ev = __builtin_amdgcn_exp2f(sT[nt][i]);
                if (MASKED)
                    ev = (krow0 + nt * 16 + quad * 4 + i <= qrow_g) ? ev : 0.0f;
                e[jh][i] = ev;
                l += ev;
            }
        }
        auto p0 = __builtin_amdgcn_cvt_pkrtz(e[0][0], e[0][1]);
        auto p1 = __builtin_amdgcn_cvt_pkrtz(e[0][2], e[0][3]);
        auto p2 = __builtin_amdgcn_cvt_pkrtz(e[1][0], e[1][1]);
        auto p3 = __builtin_amdgcn_cvt_pkrtz(e[1][2], e[1][3]);
        half8 pf;
        pf[0] = p0[0]; pf[1] = p0[1]; pf[2] = p1[0]; pf[3] = p1[1];
        pf[4] = p2[0]; pf[5] = p2[1]; pf[6] = p3[0]; pf[7] = p3[1];
#pragma unroll
        for (int dt = 0; dt < 4; ++dt) {
            half8 vf = *(const half8*)((const char*)Vs + swz(dt * 16 + c, kk * 64 + quad * 16));
            o[dt] = __builtin_amdgcn_mfma_f32_16x16x32_f16(pf, vf, o[dt], 0, 0, 0);
        }
    }
}

// ---------------------------------------------------------------- flash attention
// Mirror-paired causal q-tiles split in half: block (h, halfpair, b), wave owns
// one 16-row tile of each of qA/qB. Double-buffered KV, one barrier per iter.
__global__ __launch_bounds__(256, 4) void attn_flash5(const _Float16* __restrict__ Q,
                                                      const _Float16* __restrict__ Kg,
                                                      const _Float16* __restrict__ Vt,
                                                      _Float16* __restrict__ Ctx) {
    __shared__ __align__(16) _Float16 Ks[2 * 64 * 64];  // 16 KB dbuf
    __shared__ __align__(16) _Float16 Vs[2 * 64 * 64];  // 16 KB dbuf

    const int tid  = threadIdx.x;
    const int wave = tid >> 6;
    const int lane = tid & 63;
    const int quad = lane >> 4;
    const int c    = lane & 15;

    const int h    = blockIdx.x;
    const int hp   = blockIdx.y;
    const int bb   = blockIdx.z;
    const int pair = hp >> 1;
    const int hf   = hp & 1;

    const int qA = pair * 128 + hf * 64 + wave * 16;
    const int qB = (15 - pair) * 128 + hf * 64 + wave * 16;
    const int nkbB = (15 - pair) * 2 + hf + 1;

    const _Float16* Qb  = Q  + ((size_t)(bb * 16 + h) << 17);
    const _Float16* Kb  = Kg + ((size_t)(bb * 16 + h) << 17);
    const _Float16* Vtb = Vt + ((size_t)(bb * 16 + h) << 17);

    half8 qfA[2], qfB[2];
    {
        const _Float16* qa = Qb + (size_t)(qA + c) * 64;
        qfA[0] = *(const half8*)(qa + quad * 8);
        qfA[1] = *(const half8*)(qa + 32 + quad * 8);
        const _Float16* qb = Qb + (size_t)(qB + c) * 64;
        qfB[0] = *(const half8*)(qb + quad * 8);
        qfB[1] = *(const half8*)(qb + 32 + quad * 8);
    }

    size_t koff[2], voff[2];
#pragma unroll
    for (int it = 0; it < 2; ++it) {
        int F = it * 4096 + tid * 16;
        int r = F >> 7;
        int blk = (tid & 7) ^ (r & 7);
        koff[it] = (size_t)r * 64 + blk * 8;
        voff[it] = (size_t)r * 2048 + blk * 8;
    }

    float4v oA[4] = {}, oB[4] = {};
    float lA = 0.0f, lB = 0.0f;

    auto stage = [&](int kb, int buf) {
        const size_t kbase = (size_t)kb * 64 * 64;
#pragma unroll
        for (int it = 0; it < 2; ++it) {
            __builtin_amdgcn_global_load_lds(
                (const AS1 void*)(Kb + kbase + koff[it]),
                (AS3 void*)((char*)Ks + buf * 8192 + it * 4096 + wave * 1024), 16, 0, 0);
            __builtin_amdgcn_global_load_lds(
                (const AS1 void*)(Vtb + kb * 64 + voff[it]),
                (AS3 void*)((char*)Vs + buf * 8192 + it * 4096 + wave * 1024), 16, 0, 0);
        }
    };

    stage(0, 0);
    for (int kb = 0; kb < nkbB; ++kb) {
        __syncthreads();                       // buf kb ready; prev buf free
        if (kb + 1 < nkbB) stage(kb + 1, (kb + 1) & 1);

        const _Float16* Ksb = Ks + (kb & 1) * 4096;
        const _Float16* Vsb = Vs + (kb & 1) * 4096;
        const int krow0 = kb * 64;

        if (krow0 <= qB + 15) {
            if (krow0 + 63 <= qB)
                attn_step5<false>(qfB, Ksb, Vsb, krow0, qB, quad, c, oB, lB);
            else
                attn_step5<true >(qfB, Ksb, Vsb, krow0, qB, quad, c, oB, lB);
        }
        if (krow0 <= qA + 15) {
            if (krow0 + 63 <= qA)
                attn_step5<false>(qfA, Ksb, Vsb, krow0, qA, quad, c, oA, lA);
            else
                attn_step5<true >(qfA, Ksb, Vsb, krow0, qA, quad, c, oA, lA);
        }
    }

    // ---- l reduction across quads (lanes with same c hold same qrow)
    lA += __shfl_xor(lA, 16); lA += __shfl_xor(lA, 32);
    lB += __shfl_xor(lB, 16); lB += __shfl_xor(lB, 32);

    // ---- normalize + write ctx [b, s, h*64+hd]
#pragma unroll
    for (int t = 0; t < 2; ++t) {
        const float lv = t ? lB : lA;
        float4v* o = t ? oB : oA;
        const int qt = t ? qB : qA;
#pragma unroll
        for (int i = 0; i < 4; ++i) {
            const float inv = 1.0f / __shfl(lv, quad * 4 + i);
            const int row_g = qt + quad * 4 + i;
            _Float16* dst = Ctx + (size_t)(bb * 2048 + row_g) * 1024 + h * 64;
#pragma unroll
            for (int dt = 0; dt < 4; ++dt)
                dst[dt * 16 + c] = (_Float16)(o[dt][i] * inv);
        }
    }
}

// ---------------------------------------------------------------- launch
extern "C" void kernel_launch(void* const* d_in, const int* in_sizes, int n_in,
                              void* d_out, int out_size, void* d_ws, size_t ws_size,
                              hipStream_t stream) {
    const float* x  = (const float*)d_in[0];
    const float* Wq = (const float*)d_in[1];
    const float* Wk = (const float*)d_in[2];
    const float* Wv = (const float*)d_in[3];
    const float* Wo = (const float*)d_in[4];
    const float* bo = (const float*)d_in[5];
    float* out = (float*)d_out;

    _Float16* Xh   = (_Float16*)d_ws;
    _Float16* Wqkh = Xh + (size_t)M_ROWS * D_MODEL;      // Wq | Wk
    _Float16* Wvh  = Wqkh + (size_t)2 * D_MODEL * D_MODEL;
    _Float16* Woh  = Wvh + (size_t)D_MODEL * D_MODEL;
    _Float16* Qh   = Woh + (size_t)D_MODEL * D_MODEL;    // [b,h,s,hd], pre-scaled
    _Float16* Kh   = Qh + (size_t)M_ROWS * D_MODEL;      // [b,h,s,hd]
    _Float16* Vth  = Kh + (size_t)M_ROWS * D_MODEL;      // [b,h,hd,s'] vperm order
    _Float16* Ch   = Vth + (size_t)M_ROWS * D_MODEL;     // [b*s, d]

    const int TOT4 = (M_ROWS * D_MODEL + 4 * D_MODEL * D_MODEL) / 4;
    cvt_all<<<TOT4 / 256, 256, 0, stream>>>(x, Wq, Wk, Wv, Wo, Xh);

    gemm_bt<0><<<dim3(M_ROWS / 128, 2048 / 128), 256, 0, stream>>>(
        Xh, Wqkh, Qh, Kh, nullptr, nullptr, M_ROWS, 2048, D_MODEL);
    gemm_bt<1><<<dim3(D_MODEL / 128, M_ROWS / 128), 256, 0, stream>>>(
        Wvh, Xh, Vth, nullptr, nullptr, nullptr, D_MODEL, M_ROWS, D_MODEL);

    attn_flash5<<<dim3(N_HEADS, 16, BATCH), 256, 0, stream>>>(Qh, Kh, Vth, Ch);

    gemm_bt<2><<<dim3(M_ROWS / 128, D_MODEL / 128), 256, 0, stream>>>(
        Ch, Woh, nullptr, nullptr, out, bo, M_ROWS, D_MODEL, D_MODEL);
}